// Round 4
// baseline (200.822 us; speedup 1.0000x reference)
//
#include <hip/hip_runtime.h>
#include <hip/hip_bf16.h>
#include <stdint.h>

typedef unsigned short u16;
typedef __bf16 bf16x8_t __attribute__((ext_vector_type(8)));
typedef float f32x4_t __attribute__((ext_vector_type(4)));
typedef float f32x16_t __attribute__((ext_vector_type(16)));
typedef unsigned int u32x2_t __attribute__((ext_vector_type(2)));

// ---------- helpers ----------
__device__ __forceinline__ u16 f2bf(float f) {
    union { float f; uint32_t u; } c; c.f = f;
    uint32_t r = c.u + 0x7FFFu + ((c.u >> 16) & 1u);
    return (u16)(r >> 16);
}

__device__ __forceinline__ uint32_t pk2(float a, float b) {
    union { __bf16 h[2]; uint32_t u; } z;
    z.h[0] = (__bf16)a; z.h[1] = (__bf16)b;
    return z.u;
}

__device__ __forceinline__ void gld_lds16(const void* g, void* l) {
    __builtin_amdgcn_global_load_lds(
        (__attribute__((address_space(1))) void*)(g),
        (__attribute__((address_space(3))) void*)(l), 16, 0, 0);
}

// Q pre-scale: 1/sqrt(64) * log2(e), so attn uses raw exp2
#define QSCALE 0.18033688011112042f

// ---------- conversions ----------
__global__ void k_convert_x(const float* __restrict__ x, u16* __restrict__ xb) {
    int i = blockIdx.x * 256 + threadIdx.x;           // 2M float4 chunks exactly
    float4 v = ((const float4*)x)[i];
    ushort4 o;
    o.x = f2bf(v.x); o.y = f2bf(v.y); o.z = f2bf(v.z); o.w = f2bf(v.w);
    ((ushort4*)xb)[i] = o;
}

// transpose-convert W[in][out] fp32 -> Wt[out][in] bf16, 4 matrices (q,k,v,o)
__global__ void k_convert_wT(const float* __restrict__ w0, const float* __restrict__ w1,
                             const float* __restrict__ w2, const float* __restrict__ w3,
                             u16* __restrict__ wT) {
    __shared__ u16 t[32][33];
    const float* src = (blockIdx.z == 0) ? w0 : (blockIdx.z == 1) ? w1 : (blockIdx.z == 2) ? w2 : w3;
    u16* dst = wT + (size_t)blockIdx.z * (1024 * 1024);
    int n0 = blockIdx.x * 32, k0 = blockIdx.y * 32;
    int tx = threadIdx.x & 31, ty = threadIdx.x >> 5;  // 32 x 8
    #pragma unroll
    for (int r = 0; r < 4; ++r) {
        int kl = ty * 4 + r;
        t[tx][kl] = f2bf(src[(size_t)(k0 + kl) * 1024 + n0 + tx]);
    }
    __syncthreads();
    #pragma unroll
    for (int r = 0; r < 4; ++r) {
        int nl = ty * 4 + r;
        dst[(size_t)(n0 + nl) * 1024 + k0 + tx] = t[nl][tx];
    }
}

// ---------- GEMM: C[128x128] = A[128xK] * Bt[128xK]^T, K=1024, bf16 MFMA ----------
template <int MODE>
__global__ __launch_bounds__(256, 2) void k_gemm(
    const u16* __restrict__ A, const u16* __restrict__ WT,
    const float* __restrict__ bias,
    u16* __restrict__ qo, u16* __restrict__ ko, u16* __restrict__ vo,
    float* __restrict__ out) {
    __shared__ u16 lA[128 * 32];
    __shared__ u16 lB[128 * 32];
    const int tid = threadIdx.x, wv = tid >> 6, ln = tid & 63;
    const int lo = ln & 15, jg = ln >> 4;
    const int m0 = blockIdx.x * 128;
    int mat, n0;
    if (MODE == 0) { mat = blockIdx.y >> 3; n0 = (blockIdx.y & 7) * 128; }
    else           { mat = 3;               n0 = blockIdx.y * 128; }
    const u16* Bt = WT + (size_t)mat * (1024 * 1024);
    const int wm = wv >> 1, wn = wv & 1;

    f32x4_t acc[4][4];
    #pragma unroll
    for (int i = 0; i < 4; ++i)
        #pragma unroll
        for (int j = 0; j < 4; ++j) acc[i][j] = (f32x4_t){0.f, 0.f, 0.f, 0.f};

    for (int k0 = 0; k0 < 1024; k0 += 32) {
        __syncthreads();
        #pragma unroll
        for (int is = 0; is < 2; ++is) {
            int c = is * 256 + tid;
            int r = c >> 2;
            int j = (c & 3) ^ ((r >> 1) & 3);
            gld_lds16(A  + (size_t)(m0 + r) * 1024 + k0 + j * 8, &lA[(is * 256 + wv * 64) * 8]);
            gld_lds16(Bt + (size_t)(n0 + r) * 1024 + k0 + j * 8, &lB[(is * 256 + wv * 64) * 8]);
        }
        __syncthreads();
        bf16x8_t af[4], bfr[4];
        #pragma unroll
        for (int i = 0; i < 4; ++i) {
            int r = wm * 64 + i * 16 + lo;
            af[i] = *(const bf16x8_t*)&lA[(r * 4 + (jg ^ ((r >> 1) & 3))) * 8];
        }
        #pragma unroll
        for (int j = 0; j < 4; ++j) {
            int r = wn * 64 + j * 16 + lo;
            bfr[j] = *(const bf16x8_t*)&lB[(r * 4 + (jg ^ ((r >> 1) & 3))) * 8];
        }
        #pragma unroll
        for (int i = 0; i < 4; ++i)
            #pragma unroll
            for (int j = 0; j < 4; ++j)
                acc[i][j] = __builtin_amdgcn_mfma_f32_16x16x32_bf16(af[i], bfr[j], acc[i][j], 0, 0, 0);
    }

    if (MODE == 0) {
        u16* dst = (mat == 0) ? qo : (mat == 1) ? ko : vo;
        float sc = (mat == 0) ? QSCALE : 1.0f;
        #pragma unroll
        for (int j = 0; j < 4; ++j) {
            int col = n0 + wn * 64 + j * 16 + lo;   // 0..1023 within matrix
            int hh = col >> 6, dd = col & 63;
            #pragma unroll
            for (int i = 0; i < 4; ++i)
                #pragma unroll
                for (int rg = 0; rg < 4; ++rg) {
                    int m = m0 + wm * 64 + i * 16 + jg * 4 + rg;
                    int bb = m >> 11, nn = m & 2047;
                    dst[(((size_t)(bb * 16 + hh)) * 2048 + nn) * 64 + dd] = f2bf(acc[i][j][rg] * sc);
                }
        }
    } else {
        #pragma unroll
        for (int j = 0; j < 4; ++j) {
            int col = n0 + wn * 64 + j * 16 + lo;
            float bv = bias[col];
            #pragma unroll
            for (int i = 0; i < 4; ++i)
                #pragma unroll
                for (int rg = 0; rg < 4; ++rg) {
                    int m = m0 + wm * 64 + i * 16 + jg * 4 + rg;
                    out[(size_t)m * 1024 + col] = acc[i][j][rg] + bv;
                }
        }
    }
}

// ---------- flash attention, 32x32 MFMA, swapped QK^T, in-register P ----------
// Block: 4 waves x 32 q-rows = 128 q. KV tiles of 64, double-buffered K/V in LDS.
// grid = (64 bh, 16 qsplit): dispatch-id % 8 == bh % 8 -> all q-blocks of one
// (b,h) land on one XCD, K/V stay L2-resident per XCD.
// No-max softmax (logits pre-scaled to log2 domain via QSCALE).
// Row-sums via mfma(P, ones): lacc has the SAME lane layout as acc -> pure
// elementwise normalize, no cross-lane reduction at all.
__global__ __launch_bounds__(256, 4) void k_attn(
    const u16* __restrict__ Q, const u16* __restrict__ K,
    const u16* __restrict__ V, u16* __restrict__ ctx) {
    __shared__ __align__(16) u16 Kl[2][64 * 64];   // [key][d], XOR-swizzled 16B chunks
    __shared__ __align__(16) u16 Vt[2][64 * 64];   // [d][kv], XOR-swizzled 16B chunks

    const int tid = threadIdx.x, wv = tid >> 6, ln = tid & 63;
    const int lq = ln & 31, hi = ln >> 5;
    const int bh = blockIdx.x;
    const int b = bh >> 4, h = bh & 15;
    const size_t base = (size_t)bh * 2048 * 64;
    const int q0 = blockIdx.y * 128 + wv * 32;

    // Q fragments (B-operand of swapped QK): lane holds Q[q=lq][d=16s+8hi..+7]
    bf16x8_t bQ[4];
    {
        const u16* qp = Q + base + (size_t)(q0 + lq) * 64 + hi * 8;
        #pragma unroll
        for (int s = 0; s < 4; ++s) bQ[s] = *(const bf16x8_t*)(qp + s * 16);
    }
    bf16x8_t ones;
    #pragma unroll
    for (int e = 0; e < 8; ++e) ones[e] = (__bf16)1.0f;

    f32x16_t acc[2], lacc;
    #pragma unroll
    for (int e = 0; e < 16; ++e) { acc[0][e] = 0.f; acc[1][e] = 0.f; lacc[e] = 0.f; }

    uint4 vreg[2];

    auto stageK = [&](int buf, int kv0) {
        #pragma unroll
        for (int is = 0; is < 2; ++is) {
            int c = is * 256 + tid;
            int r = c >> 3;
            int j = (c & 7) ^ (r & 7);
            gld_lds16(K + base + (size_t)(kv0 + r) * 64 + j * 8,
                      &Kl[buf][(is * 256 + wv * 64) * 8]);
        }
    };
    auto issueV = [&](int kv0) {
        #pragma unroll
        for (int is = 0; is < 2; ++is) {
            int c = is * 256 + tid;
            int kvi = c & 63, d0 = (c >> 6) * 8;
            vreg[is] = *(const uint4*)(V + base + (size_t)(kv0 + kvi) * 64 + d0);
        }
    };
    auto writeV = [&](int buf) {
        #pragma unroll
        for (int is = 0; is < 2; ++is) {
            int c = is * 256 + tid;
            int kvi = c & 63, d0 = (c >> 6) * 8;
            int jk = kvi >> 3, klo = kvi & 7;
            union { uint4 u; u16 s[8]; } vv; vv.u = vreg[is];
            #pragma unroll
            for (int e = 0; e < 8; ++e) {
                int d = d0 + e;
                Vt[buf][d * 64 + ((jk ^ (d & 7)) * 8) + klo] = vv.s[e];
            }
        }
    };

    // prologue: stage tile 0
    stageK(0, 0);
    issueV(0);
    writeV(0);          // compiler inserts vmcnt wait on vreg use
    __syncthreads();    // also drains K gld_lds (vmcnt) before reads

    const int swl = lq & 7;

    for (int t = 0; t < 32; ++t) {
        const int c = t & 1;
        if (t < 31) {                       // T14: issue next-tile loads early
            stageK(c ^ 1, (t + 1) * 64);
            issueV((t + 1) * 64);
        }

        // per 32-key half: QK^T -> exp2 -> pack -> rowsum-mfma + PV-mfma
        #pragma unroll
        for (int kg = 0; kg < 2; ++kg) {
            f32x16_t z;
            #pragma unroll
            for (int e = 0; e < 16; ++e) z[e] = 0.f;
            __builtin_amdgcn_s_setprio(1);
            #pragma unroll
            for (int s = 0; s < 4; ++s) {
                const bf16x8_t aK = *(const bf16x8_t*)
                    &Kl[c][(kg * 32 + lq) * 64 + (((2 * s + hi) ^ swl) * 8)];
                z = __builtin_amdgcn_mfma_f32_32x32x16_bf16(aK, bQ[s], z, 0, 0, 0);
            }
            __builtin_amdgcn_s_setprio(0);
            // p = exp2(z); pack bf16 pairs (keys 8m+4hi+{0..3} at m-slot)
            uint32_t w[4][2];
            #pragma unroll
            for (int m = 0; m < 4; ++m) {
                float p0 = __builtin_amdgcn_exp2f(z[4 * m + 0]);
                float p1 = __builtin_amdgcn_exp2f(z[4 * m + 1]);
                float p2 = __builtin_amdgcn_exp2f(z[4 * m + 2]);
                float p3 = __builtin_amdgcn_exp2f(z[4 * m + 3]);
                w[m][0] = pk2(p0, p1);
                w[m][1] = pk2(p2, p3);
            }
            // PV + rowsum: A-frag via permlane32_swap of m-pairs
            __builtin_amdgcn_s_setprio(1);
            #pragma unroll
            for (int sl = 0; sl < 2; ++sl) {
                const int ma = 2 * sl, sp = 2 * kg + sl;
                u32x2_t r0 = __builtin_amdgcn_permlane32_swap(w[ma][0], w[ma + 1][0], false, false);
                u32x2_t r1 = __builtin_amdgcn_permlane32_swap(w[ma][1], w[ma + 1][1], false, false);
                union { uint32_t u[4]; bf16x8_t v; } ap;
                ap.u[0] = r0[0]; ap.u[1] = r1[0]; ap.u[2] = r0[1]; ap.u[3] = r1[1];
                lacc = __builtin_amdgcn_mfma_f32_32x32x16_bf16(ap.v, ones, lacc, 0, 0, 0);
                #pragma unroll
                for (int dh = 0; dh < 2; ++dh) {
                    const bf16x8_t bV = *(const bf16x8_t*)
                        &Vt[c][(dh * 32 + lq) * 64 + (((2 * sp + hi) ^ swl) * 8)];
                    acc[dh] = __builtin_amdgcn_mfma_f32_32x32x16_bf16(ap.v, bV, acc[dh], 0, 0, 0);
                }
            }
            __builtin_amdgcn_s_setprio(0);
        }

        if (t < 31) writeV(c ^ 1);   // vmcnt wait auto-inserted on vreg use
        __syncthreads();             // drains gld_lds + orders buffers
    }

    // ---- epilogue: elementwise normalize (lacc layout == acc layout), store bf16
    f32x16_t linv;
    #pragma unroll
    for (int e = 0; e < 16; ++e) linv[e] = 1.0f / lacc[e];
    #pragma unroll
    for (int dh = 0; dh < 2; ++dh) {
        int d = dh * 32 + lq;
        #pragma unroll
        for (int e = 0; e < 16; ++e) {
            int q = q0 + (e & 3) + 8 * (e >> 2) + 4 * hi;
            ctx[((size_t)(b * 2048 + q)) * 1024 + h * 64 + d] = f2bf(acc[dh][e] * linv[e]);
        }
    }
}

// ---------- launch ----------
extern "C" void kernel_launch(void* const* d_in, const int* in_sizes, int n_in,
                              void* d_out, int out_size, void* d_ws, size_t ws_size,
                              hipStream_t stream) {
    const float* x  = (const float*)d_in[0];
    const float* Wq = (const float*)d_in[1];
    const float* Wk = (const float*)d_in[2];
    const float* Wv = (const float*)d_in[3];
    const float* Wo = (const float*)d_in[4];
    const float* bo = (const float*)d_in[5];
    float* out = (float*)d_out;

    char* ws = (char*)d_ws;
    u16* xb   = (u16*)(ws);                 // 16 MB  [8192][1024]
    u16* wT   = (u16*)(ws + 16777216);      //  8 MB  [4][1024][1024] (q,k,v,o), [out][in]
    u16* qb   = (u16*)(ws + 25165824);      // 16 MB  [64][2048][64]
    u16* kb   = (u16*)(ws + 41943040);      // 16 MB
    u16* vb   = (u16*)(ws + 58720256);      // 16 MB
    u16* ctx  = (u16*)(ws + 75497472);      // 16 MB  [8192][1024]

    k_convert_x<<<8192, 256, 0, stream>>>(x, xb);
    k_convert_wT<<<dim3(32, 32, 4), 256, 0, stream>>>(Wq, Wk, Wv, Wo, wT);
    k_gemm<0><<<dim3(64, 24), 256, 0, stream>>>(xb, wT, nullptr, qb, kb, vb, nullptr);
    k_attn<<<dim3(64, 16), 256, 0, stream>>>(qb, kb, vb, ctx);
    k_gemm<1><<<dim3(64, 8), 256, 0, stream>>>(ctx, wT, bo, nullptr, nullptr, nullptr, out);
}

// Round 5
// 195.817 us; speedup vs baseline: 1.0256x; 1.0256x over previous
//
#include <hip/hip_runtime.h>
#include <hip/hip_bf16.h>
#include <stdint.h>

typedef unsigned short u16;
typedef __bf16 bf16x8_t __attribute__((ext_vector_type(8)));
typedef float f32x4_t __attribute__((ext_vector_type(4)));
typedef float f32x16_t __attribute__((ext_vector_type(16)));
typedef unsigned int u32x2_t __attribute__((ext_vector_type(2)));

// ---------- helpers ----------
__device__ __forceinline__ u16 f2bf(float f) {
    union { float f; uint32_t u; } c; c.f = f;
    uint32_t r = c.u + 0x7FFFu + ((c.u >> 16) & 1u);
    return (u16)(r >> 16);
}

__device__ __forceinline__ uint32_t pk2(float a, float b) {
    union { __bf16 h[2]; uint32_t u; } z;
    z.h[0] = (__bf16)a; z.h[1] = (__bf16)b;
    return z.u;
}

__device__ __forceinline__ void gld_lds16(const void* g, void* l) {
    __builtin_amdgcn_global_load_lds(
        (__attribute__((address_space(1))) void*)(g),
        (__attribute__((address_space(3))) void*)(l), 16, 0, 0);
}

// Q pre-scale: 1/sqrt(64) * log2(e), so attn uses raw exp2
#define QSCALE 0.18033688011112042f

// ---------- conversions ----------
__global__ void k_convert_x(const float* __restrict__ x, u16* __restrict__ xb) {
    int i = blockIdx.x * 256 + threadIdx.x;           // 2M float4 chunks exactly
    float4 v = ((const float4*)x)[i];
    ushort4 o;
    o.x = f2bf(v.x); o.y = f2bf(v.y); o.z = f2bf(v.z); o.w = f2bf(v.w);
    ((ushort4*)xb)[i] = o;
}

// transpose-convert W[in][out] fp32 -> Wt[out][in] bf16, 4 matrices (q,k,v,o)
__global__ void k_convert_wT(const float* __restrict__ w0, const float* __restrict__ w1,
                             const float* __restrict__ w2, const float* __restrict__ w3,
                             u16* __restrict__ wT) {
    __shared__ u16 t[32][33];
    const float* src = (blockIdx.z == 0) ? w0 : (blockIdx.z == 1) ? w1 : (blockIdx.z == 2) ? w2 : w3;
    u16* dst = wT + (size_t)blockIdx.z * (1024 * 1024);
    int n0 = blockIdx.x * 32, k0 = blockIdx.y * 32;
    int tx = threadIdx.x & 31, ty = threadIdx.x >> 5;  // 32 x 8
    #pragma unroll
    for (int r = 0; r < 4; ++r) {
        int kl = ty * 4 + r;
        t[tx][kl] = f2bf(src[(size_t)(k0 + kl) * 1024 + n0 + tx]);
    }
    __syncthreads();
    #pragma unroll
    for (int r = 0; r < 4; ++r) {
        int nl = ty * 4 + r;
        dst[(size_t)(n0 + nl) * 1024 + k0 + tx] = t[nl][tx];
    }
}

// ---------- GEMM: C[128x128] = A[128xK] * Bt[128xK]^T, K=1024, bf16 MFMA ----------
// MODE 0: A=xb, Bt=Wq/Wk/Wv^T; q scaled by QSCALE -> qo[bh][n][d];
//         k -> ko[bh][n][d]; v -> TRANSPOSED vt[bh][d][n] (ushort4 along n).
// MODE 1: A=ctx, Bt=Wo^T, write out fp32 + bias
template <int MODE>
__global__ __launch_bounds__(256, 2) void k_gemm(
    const u16* __restrict__ A, const u16* __restrict__ WT,
    const float* __restrict__ bias,
    u16* __restrict__ qo, u16* __restrict__ ko, u16* __restrict__ vt,
    float* __restrict__ out) {
    __shared__ u16 lA[128 * 32];
    __shared__ u16 lB[128 * 32];
    const int tid = threadIdx.x, wv = tid >> 6, ln = tid & 63;
    const int lo = ln & 15, jg = ln >> 4;
    const int m0 = blockIdx.x * 128;
    int mat, n0;
    if (MODE == 0) { mat = blockIdx.y >> 3; n0 = (blockIdx.y & 7) * 128; }
    else           { mat = 3;               n0 = blockIdx.y * 128; }
    const u16* Bt = WT + (size_t)mat * (1024 * 1024);
    const int wm = wv >> 1, wn = wv & 1;

    f32x4_t acc[4][4];
    #pragma unroll
    for (int i = 0; i < 4; ++i)
        #pragma unroll
        for (int j = 0; j < 4; ++j) acc[i][j] = (f32x4_t){0.f, 0.f, 0.f, 0.f};

    for (int k0 = 0; k0 < 1024; k0 += 32) {
        __syncthreads();
        #pragma unroll
        for (int is = 0; is < 2; ++is) {
            int c = is * 256 + tid;
            int r = c >> 2;
            int j = (c & 3) ^ ((r >> 1) & 3);
            gld_lds16(A  + (size_t)(m0 + r) * 1024 + k0 + j * 8, &lA[(is * 256 + wv * 64) * 8]);
            gld_lds16(Bt + (size_t)(n0 + r) * 1024 + k0 + j * 8, &lB[(is * 256 + wv * 64) * 8]);
        }
        __syncthreads();
        bf16x8_t af[4], bfr[4];
        #pragma unroll
        for (int i = 0; i < 4; ++i) {
            int r = wm * 64 + i * 16 + lo;
            af[i] = *(const bf16x8_t*)&lA[(r * 4 + (jg ^ ((r >> 1) & 3))) * 8];
        }
        #pragma unroll
        for (int j = 0; j < 4; ++j) {
            int r = wn * 64 + j * 16 + lo;
            bfr[j] = *(const bf16x8_t*)&lB[(r * 4 + (jg ^ ((r >> 1) & 3))) * 8];
        }
        #pragma unroll
        for (int i = 0; i < 4; ++i)
            #pragma unroll
            for (int j = 0; j < 4; ++j)
                acc[i][j] = __builtin_amdgcn_mfma_f32_16x16x32_bf16(af[i], bfr[j], acc[i][j], 0, 0, 0);
    }

    if (MODE == 0) {
        if (mat == 2) {
            // V: transposed write vt[bh][d][n], packed ushort4 along n
            #pragma unroll
            for (int j = 0; j < 4; ++j) {
                int col = n0 + wn * 64 + j * 16 + lo;   // h*64+d
                int hh = col >> 6, dd = col & 63;
                #pragma unroll
                for (int i = 0; i < 4; ++i) {
                    int m = m0 + wm * 64 + i * 16 + jg * 4;
                    int bb = m >> 11, nn = m & 2047;
                    ushort4 pkv;
                    pkv.x = f2bf(acc[i][j][0]);
                    pkv.y = f2bf(acc[i][j][1]);
                    pkv.z = f2bf(acc[i][j][2]);
                    pkv.w = f2bf(acc[i][j][3]);
                    *(ushort4*)&vt[(((size_t)(bb * 16 + hh)) * 64 + dd) * 2048 + nn] = pkv;
                }
            }
        } else {
            u16* dst = (mat == 0) ? qo : ko;
            float sc = (mat == 0) ? QSCALE : 1.0f;
            #pragma unroll
            for (int j = 0; j < 4; ++j) {
                int col = n0 + wn * 64 + j * 16 + lo;
                int hh = col >> 6, dd = col & 63;
                #pragma unroll
                for (int i = 0; i < 4; ++i)
                    #pragma unroll
                    for (int rg = 0; rg < 4; ++rg) {
                        int m = m0 + wm * 64 + i * 16 + jg * 4 + rg;
                        int bb = m >> 11, nn = m & 2047;
                        dst[(((size_t)(bb * 16 + hh)) * 2048 + nn) * 64 + dd] = f2bf(acc[i][j][rg] * sc);
                    }
            }
        }
    } else {
        #pragma unroll
        for (int j = 0; j < 4; ++j) {
            int col = n0 + wn * 64 + j * 16 + lo;
            float bv = bias[col];
            #pragma unroll
            for (int i = 0; i < 4; ++i)
                #pragma unroll
                for (int rg = 0; rg < 4; ++rg) {
                    int m = m0 + wm * 64 + i * 16 + jg * 4 + rg;
                    out[(size_t)m * 1024 + col] = acc[i][j][rg] + bv;
                }
        }
    }
}

// ---------- flash attention, 32x32 MFMA, swapped QK^T, in-register P ----------
// Block: 4 waves x 32 q-rows = 128 q. KV tiles of 64, double-buffered K/Vt in LDS,
// both staged with lane-linear gld_lds16 (V already transposed in HBM by k_gemm<0>).
// grid = (64 bh, 16 qsplit): dispatch-id % 8 == bh % 8 -> all q-blocks of one
// (b,h) land on one XCD, K/V stay L2-resident per XCD.
// No-max softmax (logits pre-scaled to log2 domain via QSCALE).
// Row-sums via mfma(P, ones): lacc has the SAME lane layout as acc -> pure
// elementwise normalize, no cross-lane reduction at all.
__global__ __launch_bounds__(256, 4) void k_attn(
    const u16* __restrict__ Q, const u16* __restrict__ K,
    const u16* __restrict__ Vg, u16* __restrict__ ctx) {
    __shared__ __align__(16) u16 Kl[2][64 * 64];   // [key][d], XOR-swizzled 16B chunks
    __shared__ __align__(16) u16 Vt[2][64 * 64];   // [d][kv], XOR-swizzled 16B chunks

    const int tid = threadIdx.x, wv = tid >> 6, ln = tid & 63;
    const int lq = ln & 31, hi = ln >> 5;
    const int bh = blockIdx.x;
    const int b = bh >> 4, h = bh & 15;
    const size_t base = (size_t)bh * 2048 * 64;    // for Q,K [bh][n][d]
    const u16* Vtg = Vg + (size_t)bh * 64 * 2048;  // vt [bh][d][n]
    const int q0 = blockIdx.y * 128 + wv * 32;

    // Q fragments (B-operand of swapped QK): lane holds Q[q=lq][d=16s+8hi..+7]
    bf16x8_t bQ[4];
    {
        const u16* qp = Q + base + (size_t)(q0 + lq) * 64 + hi * 8;
        #pragma unroll
        for (int s = 0; s < 4; ++s) bQ[s] = *(const bf16x8_t*)(qp + s * 16);
    }
    bf16x8_t ones;
    #pragma unroll
    for (int e = 0; e < 8; ++e) ones[e] = (__bf16)1.0f;

    f32x16_t acc[2], lacc;
    #pragma unroll
    for (int e = 0; e < 16; ++e) { acc[0][e] = 0.f; acc[1][e] = 0.f; lacc[e] = 0.f; }

    auto stageK = [&](int buf, int kv0) {
        #pragma unroll
        for (int is = 0; is < 2; ++is) {
            int c = is * 256 + tid;
            int r = c >> 3;
            int j = (c & 7) ^ (r & 7);
            gld_lds16(K + base + (size_t)(kv0 + r) * 64 + j * 8,
                      &Kl[buf][(is * 256 + wv * 64) * 8]);
        }
    };
    auto stageV = [&](int buf, int kv0) {
        #pragma unroll
        for (int is = 0; is < 2; ++is) {
            int c = is * 256 + tid;
            int r = c >> 3;                      // r = d row of vt tile
            int j = (c & 7) ^ (r & 7);
            gld_lds16(Vtg + (size_t)r * 2048 + kv0 + j * 8,
                      &Vt[buf][(is * 256 + wv * 64) * 8]);
        }
    };

    // prologue: stage tile 0
    stageK(0, 0);
    stageV(0, 0);
    __syncthreads();    // drains gld_lds (vmcnt) before reads

    const int swl = lq & 7;

    for (int t = 0; t < 32; ++t) {
        const int c = t & 1;
        if (t < 31) {                       // T14: issue next-tile loads early
            stageK(c ^ 1, (t + 1) * 64);
            stageV(c ^ 1, (t + 1) * 64);
        }

        // per 32-key half: QK^T -> exp2 -> pack -> rowsum-mfma + PV-mfma
        #pragma unroll
        for (int kg = 0; kg < 2; ++kg) {
            f32x16_t z;
            #pragma unroll
            for (int e = 0; e < 16; ++e) z[e] = 0.f;
            __builtin_amdgcn_s_setprio(1);
            #pragma unroll
            for (int s = 0; s < 4; ++s) {
                const bf16x8_t aK = *(const bf16x8_t*)
                    &Kl[c][(kg * 32 + lq) * 64 + (((2 * s + hi) ^ swl) * 8)];
                z = __builtin_amdgcn_mfma_f32_32x32x16_bf16(aK, bQ[s], z, 0, 0, 0);
            }
            __builtin_amdgcn_s_setprio(0);
            // p = exp2(z); pack bf16 pairs (keys 8m+4hi+{0..3} at m-slot)
            uint32_t w[4][2];
            #pragma unroll
            for (int m = 0; m < 4; ++m) {
                float p0 = __builtin_amdgcn_exp2f(z[4 * m + 0]);
                float p1 = __builtin_amdgcn_exp2f(z[4 * m + 1]);
                float p2 = __builtin_amdgcn_exp2f(z[4 * m + 2]);
                float p3 = __builtin_amdgcn_exp2f(z[4 * m + 3]);
                w[m][0] = pk2(p0, p1);
                w[m][1] = pk2(p2, p3);
            }
            // PV + rowsum: A-frag via permlane32_swap of m-pairs
            __builtin_amdgcn_s_setprio(1);
            #pragma unroll
            for (int sl = 0; sl < 2; ++sl) {
                const int ma = 2 * sl, sp = 2 * kg + sl;
                u32x2_t r0 = __builtin_amdgcn_permlane32_swap(w[ma][0], w[ma + 1][0], false, false);
                u32x2_t r1 = __builtin_amdgcn_permlane32_swap(w[ma][1], w[ma + 1][1], false, false);
                union { uint32_t u[4]; bf16x8_t v; } ap;
                ap.u[0] = r0[0]; ap.u[1] = r1[0]; ap.u[2] = r0[1]; ap.u[3] = r1[1];
                lacc = __builtin_amdgcn_mfma_f32_32x32x16_bf16(ap.v, ones, lacc, 0, 0, 0);
                #pragma unroll
                for (int dh = 0; dh < 2; ++dh) {
                    const bf16x8_t bV = *(const bf16x8_t*)
                        &Vt[c][(dh * 32 + lq) * 64 + (((2 * sp + hi) ^ swl) * 8)];
                    acc[dh] = __builtin_amdgcn_mfma_f32_32x32x16_bf16(ap.v, bV, acc[dh], 0, 0, 0);
                }
            }
            __builtin_amdgcn_s_setprio(0);
        }

        __syncthreads();             // drains gld_lds + orders buffers
    }

    // ---- epilogue: elementwise normalize (lacc layout == acc layout), store bf16
    f32x16_t linv;
    #pragma unroll
    for (int e = 0; e < 16; ++e) linv[e] = 1.0f / lacc[e];
    #pragma unroll
    for (int dh = 0; dh < 2; ++dh) {
        int d = dh * 32 + lq;
        #pragma unroll
        for (int e = 0; e < 16; ++e) {
            int q = q0 + (e & 3) + 8 * (e >> 2) + 4 * hi;
            ctx[((size_t)(b * 2048 + q)) * 1024 + h * 64 + d] = f2bf(acc[dh][e] * linv[e]);
        }
    }
}

// ---------- launch ----------
extern "C" void kernel_launch(void* const* d_in, const int* in_sizes, int n_in,
                              void* d_out, int out_size, void* d_ws, size_t ws_size,
                              hipStream_t stream) {
    const float* x  = (const float*)d_in[0];
    const float* Wq = (const float*)d_in[1];
    const float* Wk = (const float*)d_in[2];
    const float* Wv = (const float*)d_in[3];
    const float* Wo = (const float*)d_in[4];
    const float* bo = (const float*)d_in[5];
    float* out = (float*)d_out;

    char* ws = (char*)d_ws;
    u16* xb   = (u16*)(ws);                 // 16 MB  [8192][1024]
    u16* wT   = (u16*)(ws + 16777216);      //  8 MB  [4][1024][1024] (q,k,v,o), [out][in]
    u16* qb   = (u16*)(ws + 25165824);      // 16 MB  [64][2048][64]
    u16* kb   = (u16*)(ws + 41943040);      // 16 MB  [64][2048][64]
    u16* vtb  = (u16*)(ws + 58720256);      // 16 MB  [64][64][2048]  (V transposed)
    u16* ctx  = (u16*)(ws + 75497472);      // 16 MB  [8192][1024]

    k_convert_x<<<8192, 256, 0, stream>>>(x, xb);
    k_convert_wT<<<dim3(32, 32, 4), 256, 0, stream>>>(Wq, Wk, Wv, Wo, wT);
    k_gemm<0><<<dim3(64, 24), 256, 0, stream>>>(xb, wT, nullptr, qb, kb, vtb, nullptr);
    k_attn<<<dim3(64, 16), 256, 0, stream>>>(qb, kb, vtb, ctx);
    k_gemm<1><<<dim3(64, 8), 256, 0, stream>>>(ctx, wT, bo, nullptr, nullptr, nullptr, out);
}

// Round 6
// 171.216 us; speedup vs baseline: 1.1729x; 1.1437x over previous
//
#include <hip/hip_runtime.h>
#include <hip/hip_bf16.h>
#include <stdint.h>

typedef unsigned short u16;
typedef __bf16 bf16x8_t __attribute__((ext_vector_type(8)));
typedef float f32x4_t __attribute__((ext_vector_type(4)));
typedef float f32x16_t __attribute__((ext_vector_type(16)));
typedef unsigned int u32x2_t __attribute__((ext_vector_type(2)));

// ---------- helpers ----------
__device__ __forceinline__ u16 f2bf(float f) {
    union { float f; uint32_t u; } c; c.f = f;
    uint32_t r = c.u + 0x7FFFu + ((c.u >> 16) & 1u);
    return (u16)(r >> 16);
}

__device__ __forceinline__ uint32_t pk2(float a, float b) {
    union { __bf16 h[2]; uint32_t u; } z;
    z.h[0] = (__bf16)a; z.h[1] = (__bf16)b;
    return z.u;
}

__device__ __forceinline__ void gld_lds16(const void* g, void* l) {
    __builtin_amdgcn_global_load_lds(
        (__attribute__((address_space(1))) void*)(g),
        (__attribute__((address_space(3))) void*)(l), 16, 0, 0);
}

// Q pre-scale: 1/sqrt(64) * log2(e), so attn uses raw exp2
#define QSCALE 0.18033688011112042f

// ---------- conversions ----------
__global__ void k_convert_x(const float* __restrict__ x, u16* __restrict__ xb) {
    int i = blockIdx.x * 256 + threadIdx.x;           // 2M float4 chunks exactly
    float4 v = ((const float4*)x)[i];
    ushort4 o;
    o.x = f2bf(v.x); o.y = f2bf(v.y); o.z = f2bf(v.z); o.w = f2bf(v.w);
    ((ushort4*)xb)[i] = o;
}

// transpose-convert W[in][out] fp32 -> Wt[out][in] bf16, 4 matrices (q,k,v,o)
__global__ void k_convert_wT(const float* __restrict__ w0, const float* __restrict__ w1,
                             const float* __restrict__ w2, const float* __restrict__ w3,
                             u16* __restrict__ wT) {
    __shared__ u16 t[32][33];
    const float* src = (blockIdx.z == 0) ? w0 : (blockIdx.z == 1) ? w1 : (blockIdx.z == 2) ? w2 : w3;
    u16* dst = wT + (size_t)blockIdx.z * (1024 * 1024);
    int n0 = blockIdx.x * 32, k0 = blockIdx.y * 32;
    int tx = threadIdx.x & 31, ty = threadIdx.x >> 5;  // 32 x 8
    #pragma unroll
    for (int r = 0; r < 4; ++r) {
        int kl = ty * 4 + r;
        t[tx][kl] = f2bf(src[(size_t)(k0 + kl) * 1024 + n0 + tx]);
    }
    __syncthreads();
    #pragma unroll
    for (int r = 0; r < 4; ++r) {
        int nl = ty * 4 + r;
        dst[(size_t)(n0 + nl) * 1024 + k0 + tx] = t[nl][tx];
    }
}

// ---------- GEMM: C[128x128] = A[128xK] * Bt[128xK]^T, K=1024, BK=64, bf16 MFMA ----
// MODE 0: A=xb, Bt=Wq/Wk/Wv^T; q scaled by QSCALE -> qo[bh][n][d];
//         k -> ko[bh][n][d]; v -> TRANSPOSED vt[bh][d][n] (ushort4 along n).
// MODE 1: A=ctx, Bt=Wo^T, write out fp32 + bias
template <int MODE>
__global__ __launch_bounds__(256, 2) void k_gemm(
    const u16* __restrict__ A, const u16* __restrict__ WT,
    const float* __restrict__ bias,
    u16* __restrict__ qo, u16* __restrict__ ko, u16* __restrict__ vt,
    float* __restrict__ out) {
    __shared__ u16 lA[128 * 64];   // 16 KB, rows of 8 16B-chunks, chunk j stored at j^(r&7)
    __shared__ u16 lB[128 * 64];
    const int tid = threadIdx.x, wv = tid >> 6, ln = tid & 63;
    const int lo = ln & 15, jg = ln >> 4;
    const int m0 = blockIdx.x * 128;
    int mat, n0;
    if (MODE == 0) { mat = blockIdx.y >> 3; n0 = (blockIdx.y & 7) * 128; }
    else           { mat = 3;               n0 = blockIdx.y * 128; }
    const u16* Bt = WT + (size_t)mat * (1024 * 1024);
    const int wm = wv >> 1, wn = wv & 1;

    f32x4_t acc[4][4];
    #pragma unroll
    for (int i = 0; i < 4; ++i)
        #pragma unroll
        for (int j = 0; j < 4; ++j) acc[i][j] = (f32x4_t){0.f, 0.f, 0.f, 0.f};

    for (int k0 = 0; k0 < 1024; k0 += 64) {
        __syncthreads();
        #pragma unroll
        for (int is = 0; is < 4; ++is) {
            int c = is * 256 + tid;
            int r = c >> 3;
            int j = (c & 7) ^ (r & 7);
            gld_lds16(A  + (size_t)(m0 + r) * 1024 + k0 + j * 8, &lA[(is * 256 + wv * 64) * 8]);
            gld_lds16(Bt + (size_t)(n0 + r) * 1024 + k0 + j * 8, &lB[(is * 256 + wv * 64) * 8]);
        }
        __syncthreads();
        #pragma unroll
        for (int sub = 0; sub < 2; ++sub) {
            bf16x8_t af[4], bfr[4];
            #pragma unroll
            for (int i = 0; i < 4; ++i) {
                int r = wm * 64 + i * 16 + lo;
                af[i] = *(const bf16x8_t*)&lA[(r * 8 + ((sub * 4 + jg) ^ (r & 7))) * 8];
            }
            #pragma unroll
            for (int j = 0; j < 4; ++j) {
                int r = wn * 64 + j * 16 + lo;
                bfr[j] = *(const bf16x8_t*)&lB[(r * 8 + ((sub * 4 + jg) ^ (r & 7))) * 8];
            }
            #pragma unroll
            for (int i = 0; i < 4; ++i)
                #pragma unroll
                for (int j = 0; j < 4; ++j)
                    acc[i][j] = __builtin_amdgcn_mfma_f32_16x16x32_bf16(af[i], bfr[j], acc[i][j], 0, 0, 0);
        }
    }

    if (MODE == 0) {
        if (mat == 2) {
            // V: transposed write vt[bh][d][n], packed ushort4 along n
            #pragma unroll
            for (int j = 0; j < 4; ++j) {
                int col = n0 + wn * 64 + j * 16 + lo;   // h*64+d
                int hh = col >> 6, dd = col & 63;
                #pragma unroll
                for (int i = 0; i < 4; ++i) {
                    int m = m0 + wm * 64 + i * 16 + jg * 4;
                    int bb = m >> 11, nn = m & 2047;
                    ushort4 pkv;
                    pkv.x = f2bf(acc[i][j][0]);
                    pkv.y = f2bf(acc[i][j][1]);
                    pkv.z = f2bf(acc[i][j][2]);
                    pkv.w = f2bf(acc[i][j][3]);
                    *(ushort4*)&vt[(((size_t)(bb * 16 + hh)) * 64 + dd) * 2048 + nn] = pkv;
                }
            }
        } else {
            u16* dst = (mat == 0) ? qo : ko;
            float sc = (mat == 0) ? QSCALE : 1.0f;
            #pragma unroll
            for (int j = 0; j < 4; ++j) {
                int col = n0 + wn * 64 + j * 16 + lo;
                int hh = col >> 6, dd = col & 63;
                #pragma unroll
                for (int i = 0; i < 4; ++i)
                    #pragma unroll
                    for (int rg = 0; rg < 4; ++rg) {
                        int m = m0 + wm * 64 + i * 16 + jg * 4 + rg;
                        int bb = m >> 11, nn = m & 2047;
                        dst[(((size_t)(bb * 16 + hh)) * 2048 + nn) * 64 + dd] = f2bf(acc[i][j][rg] * sc);
                    }
            }
        }
    } else {
        #pragma unroll
        for (int j = 0; j < 4; ++j) {
            int col = n0 + wn * 64 + j * 16 + lo;
            float bv = bias[col];
            #pragma unroll
            for (int i = 0; i < 4; ++i)
                #pragma unroll
                for (int rg = 0; rg < 4; ++rg) {
                    int m = m0 + wm * 64 + i * 16 + jg * 4 + rg;
                    out[(size_t)m * 1024 + col] = acc[i][j][rg] + bv;
                }
        }
    }
}

// ---------- flash attention, 32x32 MFMA, swapped QK^T, in-register P ----------
// Block: 8 waves x 32 q-rows = 256 q (512 threads). KV tiles of 64, double-buffered
// K/Vt in LDS, both staged lane-linear via gld_lds16 (V pre-transposed in HBM).
// grid = (64 bh, 8 qsplit): dispatch-id % 8 == bh % 8 -> all q-blocks of one
// (b,h) land on one XCD, K/V stay L2-resident per XCD.
// No-max softmax (logits pre-scaled to log2 domain via QSCALE).
// Row-sums via mfma(P, ones): lacc has the SAME lane layout as acc.
__global__ __launch_bounds__(512, 4) void k_attn(
    const u16* __restrict__ Q, const u16* __restrict__ K,
    const u16* __restrict__ Vg, u16* __restrict__ ctx) {
    __shared__ __align__(16) u16 Kl[2][64 * 64];   // [key][d], XOR-swizzled 16B chunks
    __shared__ __align__(16) u16 Vt[2][64 * 64];   // [d][kv], XOR-swizzled 16B chunks

    const int tid = threadIdx.x, wv = tid >> 6, ln = tid & 63;
    const int lq = ln & 31, hi = ln >> 5;
    const int bh = blockIdx.x;
    const int b = bh >> 4, h = bh & 15;
    const size_t base = (size_t)bh * 2048 * 64;    // for Q,K [bh][n][d]
    const u16* Vtg = Vg + (size_t)bh * 64 * 2048;  // vt [bh][d][n]
    const int q0 = blockIdx.y * 256 + wv * 32;

    // Q fragments (B-operand of swapped QK): lane holds Q[q=lq][d=16s+8hi..+7]
    bf16x8_t bQ[4];
    {
        const u16* qp = Q + base + (size_t)(q0 + lq) * 64 + hi * 8;
        #pragma unroll
        for (int s = 0; s < 4; ++s) bQ[s] = *(const bf16x8_t*)(qp + s * 16);
    }
    bf16x8_t ones;
    #pragma unroll
    for (int e = 0; e < 8; ++e) ones[e] = (__bf16)1.0f;
    f32x16_t zro;
    #pragma unroll
    for (int e = 0; e < 16; ++e) zro[e] = 0.f;

    f32x16_t acc[2], lacc;
    #pragma unroll
    for (int e = 0; e < 16; ++e) { acc[0][e] = 0.f; acc[1][e] = 0.f; lacc[e] = 0.f; }

    auto stageK = [&](int buf, int kv0) {
        int r = tid >> 3;
        int j = (tid & 7) ^ (r & 7);
        gld_lds16(K + base + (size_t)(kv0 + r) * 64 + j * 8, &Kl[buf][wv * 64 * 8]);
    };
    auto stageV = [&](int buf, int kv0) {
        int r = tid >> 3;                      // r = d row of vt tile
        int j = (tid & 7) ^ (r & 7);
        gld_lds16(Vtg + (size_t)r * 2048 + kv0 + j * 8, &Vt[buf][wv * 64 * 8]);
    };

    // prologue: stage tile 0
    stageK(0, 0);
    stageV(0, 0);
    __syncthreads();    // drains gld_lds (vmcnt) before reads

    const int swl = lq & 7;

    for (int t = 0; t < 32; ++t) {
        const int c = t & 1;
        if (t < 31) {                       // T14: issue next-tile loads early
            stageK(c ^ 1, (t + 1) * 64);
            stageV(c ^ 1, (t + 1) * 64);
        }

        // per 32-key half: QK^T -> exp2 -> pack -> rowsum-mfma + PV-mfma
        #pragma unroll
        for (int kg = 0; kg < 2; ++kg) {
            f32x16_t z;
            __builtin_amdgcn_s_setprio(1);
            {
                const bf16x8_t aK = *(const bf16x8_t*)
                    &Kl[c][(kg * 32 + lq) * 64 + ((hi ^ swl) * 8)];
                z = __builtin_amdgcn_mfma_f32_32x32x16_bf16(aK, bQ[0], zro, 0, 0, 0);
            }
            #pragma unroll
            for (int s = 1; s < 4; ++s) {
                const bf16x8_t aK = *(const bf16x8_t*)
                    &Kl[c][(kg * 32 + lq) * 64 + (((2 * s + hi) ^ swl) * 8)];
                z = __builtin_amdgcn_mfma_f32_32x32x16_bf16(aK, bQ[s], z, 0, 0, 0);
            }
            __builtin_amdgcn_s_setprio(0);
            // p = exp2(z); pack bf16 pairs (keys 8m+4hi+{0..3} at m-slot)
            uint32_t w[4][2];
            #pragma unroll
            for (int m = 0; m < 4; ++m) {
                float p0 = __builtin_amdgcn_exp2f(z[4 * m + 0]);
                float p1 = __builtin_amdgcn_exp2f(z[4 * m + 1]);
                float p2 = __builtin_amdgcn_exp2f(z[4 * m + 2]);
                float p3 = __builtin_amdgcn_exp2f(z[4 * m + 3]);
                w[m][0] = pk2(p0, p1);
                w[m][1] = pk2(p2, p3);
            }
            // PV + rowsum: A-frag via permlane32_swap of m-pairs
            __builtin_amdgcn_s_setprio(1);
            #pragma unroll
            for (int sl = 0; sl < 2; ++sl) {
                const int ma = 2 * sl, sp = 2 * kg + sl;
                u32x2_t r0 = __builtin_amdgcn_permlane32_swap(w[ma][0], w[ma + 1][0], false, false);
                u32x2_t r1 = __builtin_amdgcn_permlane32_swap(w[ma][1], w[ma + 1][1], false, false);
                union { uint32_t u[4]; bf16x8_t v; } ap;
                ap.u[0] = r0[0]; ap.u[1] = r1[0]; ap.u[2] = r0[1]; ap.u[3] = r1[1];
                lacc = __builtin_amdgcn_mfma_f32_32x32x16_bf16(ap.v, ones, lacc, 0, 0, 0);
                #pragma unroll
                for (int dh = 0; dh < 2; ++dh) {
                    const bf16x8_t bV = *(const bf16x8_t*)
                        &Vt[c][(dh * 32 + lq) * 64 + (((2 * sp + hi) ^ swl) * 8)];
                    acc[dh] = __builtin_amdgcn_mfma_f32_32x32x16_bf16(ap.v, bV, acc[dh], 0, 0, 0);
                }
            }
            __builtin_amdgcn_s_setprio(0);
        }

        __syncthreads();             // drains gld_lds + orders buffers
    }

    // ---- epilogue: elementwise normalize (lacc layout == acc layout), store bf16
    f32x16_t linv;
    #pragma unroll
    for (int e = 0; e < 16; ++e) linv[e] = 1.0f / lacc[e];
    #pragma unroll
    for (int dh = 0; dh < 2; ++dh) {
        int d = dh * 32 + lq;
        #pragma unroll
        for (int e = 0; e < 16; ++e) {
            int q = q0 + (e & 3) + 8 * (e >> 2) + 4 * hi;
            ctx[((size_t)(b * 2048 + q)) * 1024 + h * 64 + d] = f2bf(acc[dh][e] * linv[e]);
        }
    }
}

// ---------- launch ----------
extern "C" void kernel_launch(void* const* d_in, const int* in_sizes, int n_in,
                              void* d_out, int out_size, void* d_ws, size_t ws_size,
                              hipStream_t stream) {
    const float* x  = (const float*)d_in[0];
    const float* Wq = (const float*)d_in[1];
    const float* Wk = (const float*)d_in[2];
    const float* Wv = (const float*)d_in[3];
    const float* Wo = (const float*)d_in[4];
    const float* bo = (const float*)d_in[5];
    float* out = (float*)d_out;

    char* ws = (char*)d_ws;
    u16* xb   = (u16*)(ws);                 // 16 MB  [8192][1024]
    u16* wT   = (u16*)(ws + 16777216);      //  8 MB  [4][1024][1024] (q,k,v,o), [out][in]
    u16* qb   = (u16*)(ws + 25165824);      // 16 MB  [64][2048][64]
    u16* kb   = (u16*)(ws + 41943040);      // 16 MB  [64][2048][64]
    u16* vtb  = (u16*)(ws + 58720256);      // 16 MB  [64][64][2048]  (V transposed)
    u16* ctx  = (u16*)(ws + 75497472);      // 16 MB  [8192][1024]

    k_convert_x<<<8192, 256, 0, stream>>>(x, xb);
    k_convert_wT<<<dim3(32, 32, 4), 256, 0, stream>>>(Wq, Wk, Wv, Wo, wT);
    k_gemm<0><<<dim3(64, 24), 256, 0, stream>>>(xb, wT, nullptr, qb, kb, vtb, nullptr);
    k_attn<<<dim3(64, 8), 512, 0, stream>>>(qb, kb, vtb, ctx);
    k_gemm<1><<<dim3(64, 8), 256, 0, stream>>>(ctx, wT, bo, nullptr, nullptr, nullptr, out);
}